// Round 1
// 662.216 us; speedup vs baseline: 1.0192x; 1.0192x over previous
//
#include <hip/hip_runtime.h>
#include <hip/hip_bf16.h>

// ---------- types ----------
typedef __bf16 bf16x8 __attribute__((ext_vector_type(8)));
typedef unsigned short u16x8 __attribute__((ext_vector_type(8)));
typedef unsigned short u16x4 __attribute__((ext_vector_type(4)));
typedef float f32x4 __attribute__((ext_vector_type(4)));
typedef __attribute__((address_space(3))) unsigned short lds_u16;

__device__ __forceinline__ unsigned short f2bf(float f) {
  unsigned u = __float_as_uint(f);
  u += 0x7FFF + ((u >> 16) & 1);   // RNE to bf16
  return (unsigned short)(u >> 16);
}
__device__ __forceinline__ unsigned short f2bf_trunc(float f) {
  return (unsigned short)(__float_as_uint(f) >> 16);  // RTZ: fine for hi/lo splits
}
__device__ __forceinline__ float bf2f(unsigned short h) {
  return __uint_as_float(((unsigned)h) << 16);
}
__device__ __forceinline__ void gl_lds16(const void* g, lds_u16* l) {
  __builtin_amdgcn_global_load_lds((const __attribute__((address_space(1))) void*)g,
                                   (__attribute__((address_space(3))) void*)l, 16, 0, 0);
}

#define T_SEQ 2048
#define HIDDEN 4096
#define NQ_HEADS 32
#define NKV_HEADS 8
#define HEAD_DIM 128
#define QKV_N 6144
#define SCALE_QK 0.08838834764831845f   /* 1/sqrt(128) */
#define SCALE_H128 0.08838834764831845f /* 1/sqrt(128) */
#define SCALE_H32 0.17677669529663687f  /* 1/sqrt(32) */

// ---------- per-row int4 fake-quant, single-pass (row cached in registers) ----------
// C == 4096 at every call site -> 4 x f32x4 per thread, no second HBM read.
__global__ __launch_bounds__(256) void quant_rows(const float* __restrict__ X,
                                                  unsigned short* __restrict__ Q,
                                                  float* __restrict__ S, int C) {
  int row = blockIdx.x;
  int tid = threadIdx.x;
  const f32x4* x4 = (const f32x4*)(X + (size_t)row * C);
  f32x4 v[4];
  float amax = 0.f;
#pragma unroll
  for (int r = 0; r < 4; r++) {
    v[r] = x4[tid + r * 256];
#pragma unroll
    for (int e = 0; e < 4; e++) amax = fmaxf(amax, fabsf(v[r][e]));
  }
#pragma unroll
  for (int mm = 1; mm < 64; mm <<= 1) amax = fmaxf(amax, __shfl_xor(amax, mm, 64));
  __shared__ float red[4];
  if ((tid & 63) == 0) red[tid >> 6] = amax;
  __syncthreads();
  amax = fmaxf(fmaxf(red[0], red[1]), fmaxf(red[2], red[3]));
  float s = fmaxf(amax / 7.0f, 1e-8f);  // exact div to match reference
#pragma unroll
  for (int r = 0; r < 4; r++) {
    u16x4 q;
#pragma unroll
    for (int e = 0; e < 4; e++) {
      float wv = rintf(v[r][e] / s);    // RNE == jnp.round, exact div
      wv = fminf(fmaxf(wv, -8.f), 7.f);
      q[e] = f2bf(wv);                  // exact (small int)
    }
    *(u16x4*)&Q[(size_t)row * C + (tid + r * 256) * 4] = q;
  }
  if (tid == 0) S[row] = s;
}

// ---------- bf16(int-code) GEMM, m97-style global_load_lds staging ----------
__global__ __launch_bounds__(256) void gemm_q4(const unsigned short* __restrict__ A,
                                               const unsigned short* __restrict__ B,
                                               const float* __restrict__ sa,
                                               const float* __restrict__ sb,
                                               const float* __restrict__ bias,
                                               float* __restrict__ C,
                                               int M, int N, int K, int hasBias) {
  __shared__ unsigned short As[128 * 32];
  __shared__ unsigned short Bs[128 * 32];
  lds_u16* As3 = (lds_u16*)As;
  lds_u16* Bs3 = (lds_u16*)Bs;
  const int tid = threadIdx.x;
  const int lane = tid & 63;
  const int w = tid >> 6;
  const int wm = w >> 1, wn = w & 1;
  const int quad = lane >> 4, l16 = lane & 15;
  const int m0 = blockIdx.y * 128, n0 = blockIdx.x * 128;

  f32x4 acc[4][4] = {};

  for (int k0 = 0; k0 < K; k0 += 32) {
    __syncthreads();
#pragma unroll
    for (int i = 0; i < 2; i++) {
      int u = (i * 4 + w) * 64 + lane;        // 16B-granule index, lane-contiguous
      int row = u >> 2;
      int col8 = (u & 3) ^ ((row >> 1) & 3);  // global-side swizzle
      gl_lds16(&A[(size_t)(m0 + row) * K + k0 + col8 * 8], &As3[(i * 4 + w) * 512]);
      gl_lds16(&B[(size_t)(n0 + row) * K + k0 + col8 * 8], &Bs3[(i * 4 + w) * 512]);
    }
    __syncthreads();
    bf16x8 af[4], bfr[4];
#pragma unroll
    for (int i = 0; i < 4; i++) {
      int ra = wm * 64 + i * 16 + l16;
      int rb = wn * 64 + i * 16 + l16;
      af[i]  = *(const bf16x8*)&As[ra * 32 + (quad ^ ((ra >> 1) & 3)) * 8];
      bfr[i] = *(const bf16x8*)&Bs[rb * 32 + (quad ^ ((rb >> 1) & 3)) * 8];
    }
#pragma unroll
    for (int i = 0; i < 4; i++)
#pragma unroll
      for (int j = 0; j < 4; j++)
        acc[i][j] = __builtin_amdgcn_mfma_f32_16x16x32_bf16(af[i], bfr[j], acc[i][j], 0, 0, 0);
  }

#pragma unroll
  for (int i = 0; i < 4; i++) {
#pragma unroll
    for (int reg = 0; reg < 4; reg++) {
      int m = m0 + wm * 64 + i * 16 + quad * 4 + reg;
      float sm = sa[m];
#pragma unroll
      for (int j = 0; j < 4; j++) {
        int n = n0 + wn * 64 + j * 16 + l16;
        float v = acc[i][j][reg] * sm * sb[n];
        if (hasBias) v += bias[n];
        C[(size_t)m * N + n] = v;
      }
    }
  }
}

// ---------- RoPE + Hadamard-128 (q,k) and plain split (v); outputs hi/lo bf16 ----------
__global__ __launch_bounds__(256) void rope_had_kernel(const int* __restrict__ pos,
                                                       const float* __restrict__ qkv,
                                                       unsigned short* __restrict__ QH, unsigned short* __restrict__ QL,
                                                       unsigned short* __restrict__ KH, unsigned short* __restrict__ KL,
                                                       unsigned short* __restrict__ VH, unsigned short* __restrict__ VL) {
  const int w = threadIdx.x >> 6, lane = threadIdx.x & 63;
  const int vec = blockIdx.x * 4 + w;   // wave-uniform branch below
  int t, h; const float* src; unsigned short *dH, *dL; size_t o; bool doRot;
  if (vec < T_SEQ * NQ_HEADS) {
    t = vec >> 5; h = vec & 31;
    src = qkv + (size_t)t * QKV_N + h * HEAD_DIM;
    dH = QH; dL = QL; o = ((size_t)t * NQ_HEADS + h) * HEAD_DIM; doRot = true;
  } else if (vec < T_SEQ * (NQ_HEADS + NKV_HEADS)) {
    int i2 = vec - T_SEQ * NQ_HEADS; t = i2 >> 3; h = i2 & 7;
    src = qkv + (size_t)t * QKV_N + 4096 + h * HEAD_DIM;
    dH = KH; dL = KL; o = ((size_t)t * NKV_HEADS + h) * HEAD_DIM; doRot = true;
  } else {
    int i2 = vec - T_SEQ * (NQ_HEADS + NKV_HEADS); t = i2 >> 3; h = i2 & 7;
    src = qkv + (size_t)t * QKV_N + 5120 + h * HEAD_DIM;
    dH = VH; dL = VL; o = ((size_t)t * NKV_HEADS + h) * HEAD_DIM; doRot = false;
  }
  float a = src[lane], b = src[lane + 64];
  if (doRot) {
    float p = (float)pos[t];
    // inv_freq = 10000^-(lane/64) = 2^(-lane * log2(1e4)/64); exp2 ~= powf to 1-2 ulp,
    // well under the bf16/int4 noise floor downstream.
    float fr = exp2f(-0.207620506f * (float)lane);
    float ang = p * fr;
    float cs = cosf(ang), sn = sinf(ang);
    float na = a * cs - b * sn;
    float nb = b * cs + a * sn;
    // FWHT-128: stride-64 stage in-register, strides 1..32 via shuffles
    a = na + nb; b = na - nb;
#pragma unroll
    for (int mm = 1; mm <= 32; mm <<= 1) {
      float pa = __shfl_xor(a, mm, 64);
      float pb = __shfl_xor(b, mm, 64);
      bool hi = (lane & mm) != 0;
      a = hi ? (pa - a) : (a + pa);
      b = hi ? (pb - b) : (b + pb);
    }
    a *= SCALE_H128; b *= SCALE_H128;
  }
  unsigned short ah = f2bf(a), bh = f2bf(b);
  dH[o + lane] = ah;       dH[o + lane + 64] = bh;
  dL[o + lane] = f2bf(a - bf2f(ah));
  dL[o + lane + 64] = f2bf(b - bf2f(bh));
}

// ---------- V transpose: [t][hk][128] hi/lo -> V^T [hk][128][2048] hi/lo ----------
__global__ __launch_bounds__(256) void vtrans_kernel(const unsigned short* __restrict__ Vh,
                                                     const unsigned short* __restrict__ Vl,
                                                     unsigned short* __restrict__ VtH,
                                                     unsigned short* __restrict__ VtL) {
  __shared__ unsigned short sm[17408];  // 2 x 64x136
  unsigned short* SH = sm;
  unsigned short* SL = sm + 8704;
  const int tid = threadIdx.x;
  const int t0 = blockIdx.x * 64, h = blockIdx.y;
#pragma unroll
  for (int r = 0; r < 4; r++) {
    int G = tid + r * 256;             // 1024 granules of 8 shorts
    int row = G >> 4, g = G & 15;
    size_t src = ((size_t)(t0 + row) * NKV_HEADS + h) * HEAD_DIM + g * 8;
    *(u16x8*)&SH[row * 136 + g * 8] = *(const u16x8*)&Vh[src];
    *(u16x8*)&SL[row * 136 + g * 8] = *(const u16x8*)&Vl[src];
  }
  __syncthreads();
#pragma unroll
  for (int r = 0; r < 4; r++) {
    int G = tid + r * 256;
    int d = G >> 3, gt = G & 7;
    u16x8 a, b;
#pragma unroll
    for (int e = 0; e < 8; e++) {
      a[e] = SH[(gt * 8 + e) * 136 + d];
      b[e] = SL[(gt * 8 + e) * 136 + d];
    }
    size_t dst = ((size_t)h * HEAD_DIM + d) * T_SEQ + t0 + gt * 8;
    *(u16x8*)&VtH[dst] = a;
    *(u16x8*)&VtL[dst] = b;
  }
}

// ---------- flash attention v5: balanced qt-pairs, XCD-local K/V, pipelined staging ----
// Grid 512 = 2 blocks/CU, every block does exactly 66 kv-tiles (pair qt=u, 31-u):
// flat makespan, no tail. XCD-contiguous mapping -> one kv-head (2 MB K/V) per XCD L2.
// K double-buffered (prefetched a full iteration ahead), V single-buffered (issued at
// iter start, consumed after S^T+softmax). Counted s_waitcnt vmcnt + raw s_barrier keep
// the K prefetch in flight ACROSS barriers (what __syncthreads' vmcnt(0) drain forbids).
__global__ __launch_bounds__(256, 2) void attn_kernel(const unsigned short* __restrict__ Qh, const unsigned short* __restrict__ Ql,
                                                      const unsigned short* __restrict__ Kh, const unsigned short* __restrict__ Kl,
                                                      const unsigned short* __restrict__ VtH, const unsigned short* __restrict__ VtL,
                                                      float* __restrict__ O) {
  __shared__ unsigned short smem[28672];   // 57344 B -> 2 blocks/CU
  // [0] K0H(4096) [4096] K0L [8192] K1H [12288] K1L   (phys g = log ^ (row&7))
  // [16384] VsH(4096) [20480] VsL                     (phys g = log ^ ((d>>1)&3))
  // [24576] Ps: per wave 1024: hi[16x32], lo[16x32]
  unsigned short* VsH = smem + 16384;
  unsigned short* VsL = smem + 20480;
  unsigned short* Ps  = smem + 24576;

  const int tid = threadIdx.x, lane = tid & 63, w = tid >> 6;
  const int quad = lane >> 4, l16 = lane & 15;

  const int b = blockIdx.x;
  const int logical = (b & 7) * 64 + (b >> 3);  // round-robin dispatch: XCD x gets heads 4x..4x+3
  const int head = logical >> 4;
  const int u = logical & 15;                   // pair id: phases run qt=u then qt=31-u
  const int hk = head >> 2;

  // staging granule geometry (per thread, buffer-relative)
  const int uk0 = tid, uk1 = tid + 256;
  const int kr0 = uk0 >> 4, kg0 = (uk0 & 15) ^ (kr0 & 7);
  const int kr1 = uk1 >> 4, kg1 = (uk1 & 15) ^ (kr1 & 7);
  const size_t ko0 = ((size_t)kr0 * NKV_HEADS + hk) * HEAD_DIM + kg0 * 8;
  const size_t ko1 = ((size_t)kr1 * NKV_HEADS + hk) * HEAD_DIM + kg1 * 8;
  const int vd0 = uk0 >> 2, vg0 = (uk0 & 3) ^ ((vd0 >> 1) & 3);
  const int vd1 = uk1 >> 2, vg1 = (uk1 & 3) ^ ((vd1 >> 1) & 3);
  const size_t vo0 = ((size_t)hk * HEAD_DIM + vd0) * T_SEQ + vg0 * 8;
  const size_t vo1 = ((size_t)hk * HEAD_DIM + vd1) * T_SEQ + vg1 * 8;
  lds_u16* dV0  = (lds_u16*)&VsH[w * 512];
  lds_u16* dV1  = (lds_u16*)&VsH[2048 + w * 512];
  lds_u16* dVL0 = (lds_u16*)&VsL[w * 512];
  lds_u16* dVL1 = (lds_u16*)&VsL[2048 + w * 512];

  unsigned short* myP = Ps + w * 1024;
  const int swP = (l16 & 3) ^ ((l16 >> 2) & 3);
  const size_t kTile = (size_t)32 * NKV_HEADS * HEAD_DIM;

#pragma unroll 1
  for (int ph = 0; ph < 2; ph++) {
    const int qt = ph ? (31 - u) : u;
    const int q0 = qt * 64;
    const int qrow = q0 + w * 16 + l16;      // this lane's q (softmax/O column)
    const int wqmax = q0 + w * 16 + 15;
    const int nkt = 2 * qt + 2;

    // Q fragments (B-operand of S^T): lane l16 = q, quad*8+j = dim
    bf16x8 qbh[4], qbl[4];
#pragma unroll
    for (int kf = 0; kf < 4; kf++) {
      size_t g = ((size_t)qrow * NQ_HEADS + head) * HEAD_DIM + kf * 32 + quad * 8;
      qbh[kf] = *(const bf16x8*)&Qh[g];
      qbl[kf] = *(const bf16x8*)&Ql[g];
    }
    f32x4 oacc[8] = {};
    float mrow = -__builtin_inff();
    float lrow = 0.f;

    // prologue: stage K tile 0 into K-buf 0. Safe: this wave is past the last barrier
    // of the previous phase, so every wave's K-buf reads (S^T) are long done.
    gl_lds16(&Kh[ko0], (lds_u16*)&smem[w * 512]);
    gl_lds16(&Kh[ko1], (lds_u16*)&smem[2048 + w * 512]);
    gl_lds16(&Kl[ko0], (lds_u16*)&smem[4096 + w * 512]);
    gl_lds16(&Kl[ko1], (lds_u16*)&smem[6144 + w * 512]);

#pragma unroll 1
    for (int kt = 0; kt < nkt; kt++) {
      const int cur = kt & 1;
      const unsigned short* KcH = smem + cur * 8192;
      const unsigned short* KcL = smem + cur * 8192 + 4096;
      // ---- barrier A: K_kt (in flight one full iteration) + V buffer free ----
      asm volatile("s_waitcnt vmcnt(0)" ::: "memory");
      __builtin_amdgcn_s_barrier();
      // issue V_kt (4 loads) FIRST, then K_{kt+1} (4 loads) -> vmcnt(4) drains V only
      {
        size_t vOff = (size_t)kt * 32;
        gl_lds16(&VtH[vOff + vo0], dV0);
        gl_lds16(&VtH[vOff + vo1], dV1);
        gl_lds16(&VtL[vOff + vo0], dVL0);
        gl_lds16(&VtL[vOff + vo1], dVL1);
      }
      const int havePref = (kt + 1 < nkt);
      if (havePref) {
        unsigned short* KnH = smem + (cur ^ 1) * 8192;
        size_t kOff = (size_t)(kt + 1) * kTile;
        gl_lds16(&Kh[kOff + ko0], (lds_u16*)&KnH[w * 512]);
        gl_lds16(&Kh[kOff + ko1], (lds_u16*)&KnH[2048 + w * 512]);
        gl_lds16(&Kl[kOff + ko0], (lds_u16*)&KnH[4096 + w * 512]);
        gl_lds16(&Kl[kOff + ko1], (lds_u16*)&KnH[6144 + w * 512]);
      }
      const bool active = (kt * 32 <= wqmax);   // wave-uniform
      f32x4 sc[2] = {};
      if (active) {
        // S^T = K . Q^T  (A=K, B=Q; D col = q = l16, row = key)
        __builtin_amdgcn_s_setprio(1);
#pragma unroll
        for (int kf = 0; kf < 4; kf++) {
          bf16x8 kah[2], kal[2];
#pragma unroll
          for (int mb = 0; mb < 2; mb++) {
            int row = mb * 16 + l16;
            int phys = (kf * 4 + quad) ^ (l16 & 7);
            kah[mb] = *(const bf16x8*)&KcH[row * 128 + phys * 8];
            kal[mb] = *(const bf16x8*)&KcL[row * 128 + phys * 8];
          }
#pragma unroll
          for (int mb = 0; mb < 2; mb++) {
            sc[mb] = __builtin_amdgcn_mfma_f32_16x16x32_bf16(kah[mb], qbh[kf], sc[mb], 0, 0, 0);
            sc[mb] = __builtin_amdgcn_mfma_f32_16x16x32_bf16(kah[mb], qbl[kf], sc[mb], 0, 0, 0);
            sc[mb] = __builtin_amdgcn_mfma_f32_16x16x32_bf16(kal[mb], qbh[kf], sc[mb], 0, 0, 0);
          }
        }
        __builtin_amdgcn_s_setprio(0);

        // causal mask, raw-score domain (diagonal tiles only; wave-uniform test)
        if (kt * 32 + 31 > q0 + w * 16) {
#pragma unroll
          for (int mb = 0; mb < 2; mb++)
#pragma unroll
            for (int r = 0; r < 4; r++) {
              int kg = kt * 32 + mb * 16 + quad * 4 + r;
              if (kg > qrow) sc[mb][r] = -__builtin_inff();
            }
        }

        // online softmax in RAW score domain; 1/sqrt(128) folded into exp via fma
        float tmax = sc[0][0];
#pragma unroll
        for (int r = 1; r < 4; r++) tmax = fmaxf(tmax, sc[0][r]);
#pragma unroll
        for (int r = 0; r < 4; r++) tmax = fmaxf(tmax, sc[1][r]);
        tmax = fmaxf(tmax, __shfl_xor(tmax, 16, 64));
        tmax = fmaxf(tmax, __shfl_xor(tmax, 32, 64));
        // defer-max (T13): skip O/l rescale while growth <= 4 in scaled domain
        // (P bounded by e^4 = 54.6; bf16 hi/lo relative precision unaffected)
        if (!__all(tmax <= mrow + 45.2548f)) {
          float mnew = fmaxf(mrow, tmax);
          float alpha = __expf((mrow - mnew) * SCALE_QK);
          mrow = mnew;
          lrow *= alpha;
#pragma unroll
          for (int nbd = 0; nbd < 8; nbd++) oacc[nbd] *= alpha;
        }
        float negm = -mrow * SCALE_QK;
        float rs = 0.f;
#pragma unroll
        for (int mb = 0; mb < 2; mb++)
#pragma unroll
          for (int r = 0; r < 4; r++) {
            float p = __expf(__builtin_fmaf(sc[mb][r], SCALE_QK, negm));
            sc[mb][r] = p;
            rs += p;
          }
        rs += __shfl_xor(rs, 16, 64);
        rs += __shfl_xor(rs, 32, 64);
        lrow += rs;

        // pack P hi/lo into per-wave LDS [q=l16 row][32 keys], swizzled b64 writes
#pragma unroll
        for (int mb = 0; mb < 2; mb++) {
          u16x4 h4, l4;
#pragma unroll
          for (int r = 0; r < 4; r++) {
            float p = sc[mb][r];
            unsigned short hsh = f2bf_trunc(p);
            h4[r] = hsh;
            l4[r] = f2bf_trunc(p - bf2f(hsh));  // residual >= 0; trunc error 2^-16 rel
          }
          int phys = (mb * 2 + (quad >> 1)) ^ swP;
          int addr = l16 * 32 + phys * 8 + (quad & 1) * 4;
          *(u16x4*)&myP[addr] = h4;
          *(u16x4*)&myP[512 + addr] = l4;
        }
      }
      // ---- barrier B: own V drained (K prefetch STAYS in flight), V visible to all ----
      if (havePref) asm volatile("s_waitcnt vmcnt(4)" ::: "memory");
      else          asm volatile("s_waitcnt vmcnt(0)" ::: "memory");
      __builtin_amdgcn_s_barrier();
      if (active) {
        // O^T += V^T . P  (A=V^T, B=P; D col = q = l16, row = d)
        bf16x8 pbh = *(const bf16x8*)&myP[l16 * 32 + (quad ^ swP) * 8];
        bf16x8 pbl = *(const bf16x8*)&myP[512 + l16 * 32 + (quad ^ swP) * 8];
        __builtin_amdgcn_s_setprio(1);
#pragma unroll
        for (int nbd = 0; nbd < 8; nbd++) {
          int d = nbd * 16 + l16;
          int physv = quad ^ ((d >> 1) & 3);
          bf16x8 vah = *(const bf16x8*)&VsH[d * 32 + physv * 8];
          bf16x8 val = *(const bf16x8*)&VsL[d * 32 + physv * 8];
          f32x4 t = oacc[nbd];
          t = __builtin_amdgcn_mfma_f32_16x16x32_bf16(vah, pbh, t, 0, 0, 0);
          t = __builtin_amdgcn_mfma_f32_16x16x32_bf16(vah, pbl, t, 0, 0, 0);
          t = __builtin_amdgcn_mfma_f32_16x16x32_bf16(val, pbh, t, 0, 0, 0);
          oacc[nbd] = t;
        }
        __builtin_amdgcn_s_setprio(0);
      }
    }

    // phase epilogue: per-lane normalize; float4 stores (d = nbd*16 + quad*4 + r)
    float inv = 1.0f / lrow;
#pragma unroll
    for (int nbd = 0; nbd < 8; nbd++) {
      f32x4 o = oacc[nbd] * inv;
      *(f32x4*)&O[((size_t)qrow * NQ_HEADS + head) * HEAD_DIM + nbd * 16 + quad * 4] = o;
    }
  }
}

// ---------- head-Hadamard (32) + per-token int4 fake-quant ----------
__global__ __launch_bounds__(128) void headhad_quant(const float* __restrict__ attn,
                                                     unsigned short* __restrict__ Aq,
                                                     float* __restrict__ Sa) {
  const int t = blockIdx.x, d = threadIdx.x; // 128 threads, one d-column each
  float x[32];
#pragma unroll
  for (int h = 0; h < 32; h++) x[h] = attn[(size_t)t * 4096 + h * 128 + d];
#pragma unroll
  for (int s = 1; s < 32; s <<= 1) {
#pragma unroll
    for (int i = 0; i < 32; i++) {
      if (!(i & s)) {
        float u = x[i], v = x[i | s];
        x[i] = u + v; x[i | s] = u - v;
      }
    }
  }
  float amax = 0.f;
#pragma unroll
  for (int h = 0; h < 32; h++) { x[h] *= SCALE_H32; amax = fmaxf(amax, fabsf(x[h])); }
#pragma unroll
  for (int mm = 1; mm < 64; mm <<= 1) amax = fmaxf(amax, __shfl_xor(amax, mm, 64));
  __shared__ float red[2];
  if ((threadIdx.x & 63) == 0) red[threadIdx.x >> 6] = amax;
  __syncthreads();
  amax = fmaxf(red[0], red[1]);
  float s = fmaxf(amax / 7.0f, 1e-8f);
#pragma unroll
  for (int h = 0; h < 32; h++) {
    float q = rintf(x[h] / s);
    q = fminf(fmaxf(q, -8.f), 7.f);
    Aq[(size_t)t * 4096 + h * 128 + d] = f2bf(q);
  }
  if (threadIdx.x == 0) Sa[t] = s;
}

// ---------- launch ----------
extern "C" void kernel_launch(void* const* d_in, const int* in_sizes, int n_in,
                              void* d_out, int out_size, void* d_ws, size_t ws_size,
                              hipStream_t stream) {
  const int*   positions = (const int*)d_in[0];
  const float* hidden    = (const float*)d_in[1];
  const float* qkv_w     = (const float*)d_in[2];
  const float* qkv_b     = (const float*)d_in[3];
  const float* o_w       = (const float*)d_in[4];
  float* out = (float*)d_out;
  char* ws = (char*)d_ws;

  // region map (total ~160.1 MB)
  unsigned short* wq   = (unsigned short*)(ws + 0);          // 6144x4096 bf16 ; later owq 4096x4096
  unsigned short* xq   = (unsigned short*)(ws + 50331648);   // 2048x4096 bf16 ; later vth/vtl then aq
  float*          qkv  = (float*)(ws + 67108864);            // 2048x6144 f32 ; later attn f32
  unsigned short* qh   = (unsigned short*)(ws + 117440512);  // 2048x32x128
  unsigned short* ql   = (unsigned short*)(ws + 134217728);
  unsigned short* kh   = (unsigned short*)(ws + 150994944);  // 2048x8x128
  unsigned short* kl   = (unsigned short*)(ws + 155189248);
  unsigned short* vh   = (unsigned short*)(ws + 159383552);
  unsigned short* vl   = (unsigned short*)(ws + 163577856);
  float* s_x  = (float*)(ws + 167772160);
  float* s_w  = (float*)(ws + 167780352);
  float* s_a  = (float*)(ws + 167804928);
  float* s_ow = (float*)(ws + 167813120);
  unsigned short* owq  = wq;                                 // reuse R0 after GEMM1
  unsigned short* aq   = xq;                                 // reuse R1 after attn
  unsigned short* vth  = (unsigned short*)(ws + 50331648);   // inside R1 (xq dead after GEMM1)
  unsigned short* vtl  = (unsigned short*)(ws + 54525952);
  float* attnbuf       = qkv;                                // reuse R2 after rope

  // 1. quantize activations + qkv weights (single-pass)
  quant_rows<<<T_SEQ, 256, 0, stream>>>(hidden, xq, s_x, HIDDEN);
  quant_rows<<<QKV_N, 256, 0, stream>>>(qkv_w, wq, s_w, HIDDEN);
  // 2. QKV GEMM (exact int4 dot in bf16 MFMA)
  gemm_q4<<<dim3(QKV_N / 128, T_SEQ / 128), 256, 0, stream>>>(xq, wq, s_x, s_w, qkv_b,
                                                              qkv, T_SEQ, QKV_N, HIDDEN, 1);
  // 3. RoPE + Hadamard-128, hi/lo split outputs
  rope_had_kernel<<<(T_SEQ * 48) / 4, 256, 0, stream>>>(positions, qkv, qh, ql, kh, kl, vh, vl);
  // 3b. V transpose into [hk][d][t] (R1 is free now)
  vtrans_kernel<<<dim3(T_SEQ / 64, NKV_HEADS), 256, 0, stream>>>(vh, vl, vth, vtl);
  // 4. quantize o_w (into reused R0)
  quant_rows<<<HIDDEN, 256, 0, stream>>>(o_w, owq, s_ow, HIDDEN);
  // 5. attention (emulated-fp32), balanced-pair grid, writes attn into reused R2
  attn_kernel<<<dim3(512), 256, 0, stream>>>(qh, ql, kh, kl, vth, vtl, attnbuf);
  // 6. head-Hadamard + per-token fake-quant (into reused R1; vth/vtl dead)
  headhad_quant<<<T_SEQ, 128, 0, stream>>>(attnbuf, aq, s_a);
  // 7. O-proj GEMM
  gemm_q4<<<dim3(HIDDEN / 128, T_SEQ / 128), 256, 0, stream>>>(aq, owq, s_a, s_ow, nullptr,
                                                               out, T_SEQ, HIDDEN, HIDDEN, 0);
}

// Round 2
// 642.090 us; speedup vs baseline: 1.0511x; 1.0313x over previous
//
#include <hip/hip_runtime.h>
#include <hip/hip_bf16.h>

// ---------- types ----------
typedef __bf16 bf16x8 __attribute__((ext_vector_type(8)));
typedef unsigned short u16x8 __attribute__((ext_vector_type(8)));
typedef unsigned short u16x4 __attribute__((ext_vector_type(4)));
typedef float f32x4 __attribute__((ext_vector_type(4)));
typedef __attribute__((address_space(3))) unsigned short lds_u16;

__device__ __forceinline__ unsigned short f2bf(float f) {
  unsigned u = __float_as_uint(f);
  u += 0x7FFF + ((u >> 16) & 1);   // RNE to bf16
  return (unsigned short)(u >> 16);
}
__device__ __forceinline__ unsigned short f2bf_trunc(float f) {
  return (unsigned short)(__float_as_uint(f) >> 16);  // RTZ: fine for hi/lo splits
}
__device__ __forceinline__ float bf2f(unsigned short h) {
  return __uint_as_float(((unsigned)h) << 16);
}
__device__ __forceinline__ void gl_lds16(const void* g, lds_u16* l) {
  __builtin_amdgcn_global_load_lds((const __attribute__((address_space(1))) void*)g,
                                   (__attribute__((address_space(3))) void*)l, 16, 0, 0);
}

#define T_SEQ 2048
#define HIDDEN 4096
#define NQ_HEADS 32
#define NKV_HEADS 8
#define HEAD_DIM 128
#define QKV_N 6144
#define SCALE_QK 0.08838834764831845f   /* 1/sqrt(128) */
#define SCALE_H128 0.08838834764831845f /* 1/sqrt(128) */
#define SCALE_H32 0.17677669529663687f  /* 1/sqrt(32) */

// ---------- per-row int4 fake-quant, single-pass (row cached in registers) ----------
__global__ __launch_bounds__(256) void quant_rows(const float* __restrict__ X,
                                                  unsigned short* __restrict__ Q,
                                                  float* __restrict__ S, int C) {
  int row = blockIdx.x;
  int tid = threadIdx.x;
  const f32x4* x4 = (const f32x4*)(X + (size_t)row * C);
  f32x4 v[4];
  float amax = 0.f;
#pragma unroll
  for (int r = 0; r < 4; r++) {
    v[r] = x4[tid + r * 256];
#pragma unroll
    for (int e = 0; e < 4; e++) amax = fmaxf(amax, fabsf(v[r][e]));
  }
#pragma unroll
  for (int mm = 1; mm < 64; mm <<= 1) amax = fmaxf(amax, __shfl_xor(amax, mm, 64));
  __shared__ float red[4];
  if ((tid & 63) == 0) red[tid >> 6] = amax;
  __syncthreads();
  amax = fmaxf(fmaxf(red[0], red[1]), fmaxf(red[2], red[3]));
  float s = fmaxf(amax / 7.0f, 1e-8f);  // exact div to match reference
#pragma unroll
  for (int r = 0; r < 4; r++) {
    u16x4 q;
#pragma unroll
    for (int e = 0; e < 4; e++) {
      float wv = rintf(v[r][e] / s);    // RNE == jnp.round, exact div
      wv = fminf(fmaxf(wv, -8.f), 7.f);
      q[e] = f2bf(wv);                  // exact (small int)
    }
    *(u16x4*)&Q[(size_t)row * C + (tid + r * 256) * 4] = q;
  }
  if (tid == 0) S[row] = s;
}

// ---------- bf16(int-code) GEMM, m97-style global_load_lds staging ----------
__global__ __launch_bounds__(256) void gemm_q4(const unsigned short* __restrict__ A,
                                               const unsigned short* __restrict__ B,
                                               const float* __restrict__ sa,
                                               const float* __restrict__ sb,
                                               const float* __restrict__ bias,
                                               float* __restrict__ C,
                                               int M, int N, int K, int hasBias) {
  __shared__ unsigned short As[128 * 32];
  __shared__ unsigned short Bs[128 * 32];
  lds_u16* As3 = (lds_u16*)As;
  lds_u16* Bs3 = (lds_u16*)Bs;
  const int tid = threadIdx.x;
  const int lane = tid & 63;
  const int w = tid >> 6;
  const int wm = w >> 1, wn = w & 1;
  const int quad = lane >> 4, l16 = lane & 15;
  const int m0 = blockIdx.y * 128, n0 = blockIdx.x * 128;

  f32x4 acc[4][4] = {};

  for (int k0 = 0; k0 < K; k0 += 32) {
    __syncthreads();
#pragma unroll
    for (int i = 0; i < 2; i++) {
      int u = (i * 4 + w) * 64 + lane;        // 16B-granule index, lane-contiguous
      int row = u >> 2;
      int col8 = (u & 3) ^ ((row >> 1) & 3);  // global-side swizzle
      gl_lds16(&A[(size_t)(m0 + row) * K + k0 + col8 * 8], &As3[(i * 4 + w) * 512]);
      gl_lds16(&B[(size_t)(n0 + row) * K + k0 + col8 * 8], &Bs3[(i * 4 + w) * 512]);
    }
    __syncthreads();
    bf16x8 af[4], bfr[4];
#pragma unroll
    for (int i = 0; i < 4; i++) {
      int ra = wm * 64 + i * 16 + l16;
      int rb = wn * 64 + i * 16 + l16;
      af[i]  = *(const bf16x8*)&As[ra * 32 + (quad ^ ((ra >> 1) & 3)) * 8];
      bfr[i] = *(const bf16x8*)&Bs[rb * 32 + (quad ^ ((rb >> 1) & 3)) * 8];
    }
#pragma unroll
    for (int i = 0; i < 4; i++)
#pragma unroll
      for (int j = 0; j < 4; j++)
        acc[i][j] = __builtin_amdgcn_mfma_f32_16x16x32_bf16(af[i], bfr[j], acc[i][j], 0, 0, 0);
  }

#pragma unroll
  for (int i = 0; i < 4; i++) {
#pragma unroll
    for (int reg = 0; reg < 4; reg++) {
      int m = m0 + wm * 64 + i * 16 + quad * 4 + reg;
      float sm = sa[m];
#pragma unroll
      for (int j = 0; j < 4; j++) {
        int n = n0 + wn * 64 + j * 16 + l16;
        float v = acc[i][j][reg] * sm * sb[n];
        if (hasBias) v += bias[n];
        C[(size_t)m * N + n] = v;
      }
    }
  }
}

// ---------- RoPE + Hadamard-128 (q,k) and plain split (v); outputs hi/lo bf16 ----------
__global__ __launch_bounds__(256) void rope_had_kernel(const int* __restrict__ pos,
                                                       const float* __restrict__ qkv,
                                                       unsigned short* __restrict__ QH, unsigned short* __restrict__ QL,
                                                       unsigned short* __restrict__ KH, unsigned short* __restrict__ KL,
                                                       unsigned short* __restrict__ VH, unsigned short* __restrict__ VL) {
  const int w = threadIdx.x >> 6, lane = threadIdx.x & 63;
  const int vec = blockIdx.x * 4 + w;   // wave-uniform branch below
  int t, h; const float* src; unsigned short *dH, *dL; size_t o; bool doRot;
  if (vec < T_SEQ * NQ_HEADS) {
    t = vec >> 5; h = vec & 31;
    src = qkv + (size_t)t * QKV_N + h * HEAD_DIM;
    dH = QH; dL = QL; o = ((size_t)t * NQ_HEADS + h) * HEAD_DIM; doRot = true;
  } else if (vec < T_SEQ * (NQ_HEADS + NKV_HEADS)) {
    int i2 = vec - T_SEQ * NQ_HEADS; t = i2 >> 3; h = i2 & 7;
    src = qkv + (size_t)t * QKV_N + 4096 + h * HEAD_DIM;
    dH = KH; dL = KL; o = ((size_t)t * NKV_HEADS + h) * HEAD_DIM; doRot = true;
  } else {
    int i2 = vec - T_SEQ * (NQ_HEADS + NKV_HEADS); t = i2 >> 3; h = i2 & 7;
    src = qkv + (size_t)t * QKV_N + 5120 + h * HEAD_DIM;
    dH = VH; dL = VL; o = ((size_t)t * NKV_HEADS + h) * HEAD_DIM; doRot = false;
  }
  float a = src[lane], b = src[lane + 64];
  if (doRot) {
    float p = (float)pos[t];
    float fr = exp2f(-0.207620506f * (float)lane);   // 10000^-(lane/64)
    float ang = p * fr;
    float cs = cosf(ang), sn = sinf(ang);
    float na = a * cs - b * sn;
    float nb = b * cs + a * sn;
    // FWHT-128: stride-64 stage in-register, strides 1..32 via shuffles
    a = na + nb; b = na - nb;
#pragma unroll
    for (int mm = 1; mm <= 32; mm <<= 1) {
      float pa = __shfl_xor(a, mm, 64);
      float pb = __shfl_xor(b, mm, 64);
      bool hi = (lane & mm) != 0;
      a = hi ? (pa - a) : (a + pa);
      b = hi ? (pb - b) : (b + pb);
    }
    a *= SCALE_H128; b *= SCALE_H128;
  }
  unsigned short ah = f2bf(a), bh = f2bf(b);
  dH[o + lane] = ah;       dH[o + lane + 64] = bh;
  dL[o + lane] = f2bf(a - bf2f(ah));
  dL[o + lane + 64] = f2bf(b - bf2f(bh));
}

// ---------- V transpose: [t][hk][128] hi/lo -> V^T [hk][128][2048] hi/lo ----------
__global__ __launch_bounds__(256) void vtrans_kernel(const unsigned short* __restrict__ Vh,
                                                     const unsigned short* __restrict__ Vl,
                                                     unsigned short* __restrict__ VtH,
                                                     unsigned short* __restrict__ VtL) {
  __shared__ unsigned short sm[17408];  // 2 x 64x136
  unsigned short* SH = sm;
  unsigned short* SL = sm + 8704;
  const int tid = threadIdx.x;
  const int t0 = blockIdx.x * 64, h = blockIdx.y;
#pragma unroll
  for (int r = 0; r < 4; r++) {
    int G = tid + r * 256;             // 1024 granules of 8 shorts
    int row = G >> 4, g = G & 15;
    size_t src = ((size_t)(t0 + row) * NKV_HEADS + h) * HEAD_DIM + g * 8;
    *(u16x8*)&SH[row * 136 + g * 8] = *(const u16x8*)&Vh[src];
    *(u16x8*)&SL[row * 136 + g * 8] = *(const u16x8*)&Vl[src];
  }
  __syncthreads();
#pragma unroll
  for (int r = 0; r < 4; r++) {
    int G = tid + r * 256;
    int d = G >> 3, gt = G & 7;
    u16x8 a, b;
#pragma unroll
    for (int e = 0; e < 8; e++) {
      a[e] = SH[(gt * 8 + e) * 136 + d];
      b[e] = SL[(gt * 8 + e) * 136 + d];
    }
    size_t dst = ((size_t)h * HEAD_DIM + d) * T_SEQ + t0 + gt * 8;
    *(u16x8*)&VtH[dst] = a;
    *(u16x8*)&VtL[dst] = b;
  }
}

// ---------- flash attention v6: 2-head blocks, full K+V double-buffer, 1 barrier/tile -
// 256 blocks x 512 threads (1 block/CU, 8 waves). Waves 0-3 = head A, 4-7 = head B: the
// two q-heads share every staged K/V tile -> staging bytes, staging instructions and
// barriers are HALVED per MFMA. K and V are both double-buffered and prefetched a full
// iteration ahead; P is wave-private; so each tile needs exactly ONE
// {vmcnt(0); s_barrier} (all waves drain their own prefetch before the rendezvous ->
// race-free with uniform barrier counts). Phase-1 tile 0 is prefetched from phase-0's
// last iteration (one cold start per block). hk = b&7 keeps one kv-head per XCD L2.
__global__ __launch_bounds__(512, 2) void attn_kernel(const unsigned short* __restrict__ Qh, const unsigned short* __restrict__ Ql,
                                                      const unsigned short* __restrict__ Kh, const unsigned short* __restrict__ Kl,
                                                      const unsigned short* __restrict__ VtH, const unsigned short* __restrict__ VtL,
                                                      float* __restrict__ O) {
  __shared__ unsigned short smem[40960];   // 81920 B
  // K buf c: [c*8192, c*8192+4096) = KH, +4096 = KL   (phys g = log ^ (row&7))
  // V buf c: 16384 + c*8192: VH, +4096 = VL           (phys g = log ^ ((d>>1)&3))
  // Ps: 32768 + w*1024 per wave: hi[16x32], lo[16x32]
  const int tid = threadIdx.x, lane = tid & 63, w = tid >> 6;
  const int quad = lane >> 4, l16 = lane & 15;

  const int b = blockIdx.x;
  const int hk = b & 7;                  // round-robin dispatch: XCD x owns kv-head x
  const int idx = b >> 3;                // 0..31
  const int hp = idx & 1;                // head pair within kv-group
  const int u = idx >> 1;                // 0..15 ; phases run qt=u then qt=31-u
  const int head = hk * 4 + hp * 2 + (w >> 2);
  const int ww = w & 3;                  // q-row group within the 64-row tile

  // staging granule geometry (per thread, buffer-relative); 512 granules per matrix
  const int kr = tid >> 4, kg = (tid & 15) ^ (kr & 7);
  const size_t ko = ((size_t)kr * NKV_HEADS + hk) * HEAD_DIM + kg * 8;
  const int vd = tid >> 2, vg = (tid & 3) ^ ((vd >> 1) & 3);
  const size_t vo = ((size_t)hk * HEAD_DIM + vd) * T_SEQ + vg * 8;
  const size_t kTile = (size_t)32 * NKV_HEADS * HEAD_DIM;

  unsigned short* myP = smem + 32768 + w * 1024;
  const int swP = (l16 & 3) ^ ((l16 >> 2) & 3);

#pragma unroll 1
  for (int ph = 0; ph < 2; ph++) {
    const int qt = ph ? (31 - u) : u;
    const int q0 = qt * 64;
    const int qrow = q0 + ww * 16 + l16;     // this lane's q (softmax/O column)
    const int wqmax = q0 + ww * 16 + 15;
    const int nkt = 2 * qt + 2;

    // Q fragments (B-operand of S^T): lane l16 = q, quad*8+j = dim
    bf16x8 qbh[4], qbl[4];
#pragma unroll
    for (int kf = 0; kf < 4; kf++) {
      size_t g = ((size_t)qrow * NQ_HEADS + head) * HEAD_DIM + kf * 32 + quad * 8;
      qbh[kf] = *(const bf16x8*)&Qh[g];
      qbl[kf] = *(const bf16x8*)&Ql[g];
    }
    f32x4 oacc[8] = {};
    float mrow = -__builtin_inff();
    float lrow = 0.f;

    if (ph == 0) {
      // cold start: stage tile 0 into buf 0 (phase-1 tile 0 is staged by phase-0's
      // last iteration, so this runs once per block)
      gl_lds16(&Kh[ko],  (lds_u16*)&smem[w * 512]);
      gl_lds16(&Kl[ko],  (lds_u16*)&smem[4096 + w * 512]);
      gl_lds16(&VtH[vo], (lds_u16*)&smem[16384 + w * 512]);
      gl_lds16(&VtL[vo], (lds_u16*)&smem[16384 + 4096 + w * 512]);
    }

#pragma unroll 1
    for (int kt = 0; kt < nkt; kt++) {
      const int cur = kt & 1;
      const unsigned short* KcH = smem + cur * 8192;
      const unsigned short* KcL = KcH + 4096;
      const unsigned short* VcH = smem + 16384 + cur * 8192;
      const unsigned short* VcL = VcH + 4096;
      // ---- the one barrier: own prefetch (aged a full iteration) drained, then
      // rendezvous -> tile kt resident in LDS for all waves; prev buffer free ----
      asm volatile("s_waitcnt vmcnt(0)" ::: "memory");
      __builtin_amdgcn_s_barrier();
      // prefetch next tile (tile kt+1, or phase-1 tile 0 from phase-0's last iter)
      {
        int tn = -1;
        if (kt + 1 < nkt) tn = kt + 1;
        else if (ph == 0) tn = 0;            // phase-1 tile 0 -> buf 0 (parity: nkt even)
        if (tn >= 0) {
          const int nb = tn & 1;
          unsigned short* KnB = smem + nb * 8192;
          unsigned short* VnB = smem + 16384 + nb * 8192;
          size_t kOff = (size_t)tn * kTile;
          size_t vOff = (size_t)tn * 32;
          gl_lds16(&Kh[kOff + ko],  (lds_u16*)&KnB[w * 512]);
          gl_lds16(&Kl[kOff + ko],  (lds_u16*)&KnB[4096 + w * 512]);
          gl_lds16(&VtH[vOff + vo], (lds_u16*)&VnB[w * 512]);
          gl_lds16(&VtL[vOff + vo], (lds_u16*)&VnB[4096 + w * 512]);
        }
      }
      const bool active = (kt * 32 <= wqmax);   // wave-uniform
      if (!active) continue;

      // S^T = K . Q^T  (A=K, B=Q; D col = q = l16, row = key)
      f32x4 sc[2] = {};
      __builtin_amdgcn_s_setprio(1);
#pragma unroll
      for (int kf = 0; kf < 4; kf++) {
        bf16x8 kah[2], kal[2];
#pragma unroll
        for (int mb = 0; mb < 2; mb++) {
          int row = mb * 16 + l16;
          int phys = (kf * 4 + quad) ^ (l16 & 7);
          kah[mb] = *(const bf16x8*)&KcH[row * 128 + phys * 8];
          kal[mb] = *(const bf16x8*)&KcL[row * 128 + phys * 8];
        }
#pragma unroll
        for (int mb = 0; mb < 2; mb++) {
          sc[mb] = __builtin_amdgcn_mfma_f32_16x16x32_bf16(kah[mb], qbh[kf], sc[mb], 0, 0, 0);
          sc[mb] = __builtin_amdgcn_mfma_f32_16x16x32_bf16(kah[mb], qbl[kf], sc[mb], 0, 0, 0);
          sc[mb] = __builtin_amdgcn_mfma_f32_16x16x32_bf16(kal[mb], qbh[kf], sc[mb], 0, 0, 0);
        }
      }
      __builtin_amdgcn_s_setprio(0);

      // causal mask, raw-score domain (diagonal tiles only; wave-uniform test)
      if (kt * 32 + 31 > q0 + ww * 16) {
#pragma unroll
        for (int mb = 0; mb < 2; mb++)
#pragma unroll
          for (int r = 0; r < 4; r++) {
            int kg2 = kt * 32 + mb * 16 + quad * 4 + r;
            if (kg2 > qrow) sc[mb][r] = -__builtin_inff();
          }
      }

      // online softmax in RAW score domain; 1/sqrt(128) folded into exp via fma
      float tmax = sc[0][0];
#pragma unroll
      for (int r = 1; r < 4; r++) tmax = fmaxf(tmax, sc[0][r]);
#pragma unroll
      for (int r = 0; r < 4; r++) tmax = fmaxf(tmax, sc[1][r]);
      tmax = fmaxf(tmax, __shfl_xor(tmax, 16, 64));
      tmax = fmaxf(tmax, __shfl_xor(tmax, 32, 64));
      // defer-max (T13): skip O/l rescale while growth <= 4 in scaled domain
      if (!__all(tmax <= mrow + 45.2548f)) {
        float mnew = fmaxf(mrow, tmax);
        float alpha = __expf((mrow - mnew) * SCALE_QK);
        mrow = mnew;
        lrow *= alpha;
#pragma unroll
        for (int nbd = 0; nbd < 8; nbd++) oacc[nbd] *= alpha;
      }
      float negm = -mrow * SCALE_QK;
      float rs = 0.f;
#pragma unroll
      for (int mb = 0; mb < 2; mb++)
#pragma unroll
        for (int r = 0; r < 4; r++) {
          float p = __expf(__builtin_fmaf(sc[mb][r], SCALE_QK, negm));
          sc[mb][r] = p;
          rs += p;
        }
      rs += __shfl_xor(rs, 16, 64);
      rs += __shfl_xor(rs, 32, 64);
      lrow += rs;

      // pack P hi/lo into per-wave LDS [q=l16 row][32 keys], swizzled b64 writes
#pragma unroll
      for (int mb = 0; mb < 2; mb++) {
        u16x4 h4, l4;
#pragma unroll
        for (int r = 0; r < 4; r++) {
          float p = sc[mb][r];
          unsigned short hsh = f2bf_trunc(p);
          h4[r] = hsh;
          l4[r] = f2bf_trunc(p - bf2f(hsh));  // residual >= 0; trunc err 2^-16 rel
        }
        int phys = (mb * 2 + (quad >> 1)) ^ swP;
        int addr = l16 * 32 + phys * 8 + (quad & 1) * 4;
        *(u16x4*)&myP[addr] = h4;
        *(u16x4*)&myP[512 + addr] = l4;
      }

      // O^T += V^T . P  (A=V^T, B=P; D col = q = l16, row = d); V resident (prefetched)
      bf16x8 pbh = *(const bf16x8*)&myP[l16 * 32 + (quad ^ swP) * 8];
      bf16x8 pbl = *(const bf16x8*)&myP[512 + l16 * 32 + (quad ^ swP) * 8];
      __builtin_amdgcn_s_setprio(1);
#pragma unroll
      for (int nbd = 0; nbd < 8; nbd++) {
        int d = nbd * 16 + l16;
        int physv = quad ^ ((d >> 1) & 3);
        bf16x8 vah = *(const bf16x8*)&VcH[d * 32 + physv * 8];
        bf16x8 val = *(const bf16x8*)&VcL[d * 32 + physv * 8];
        f32x4 t = oacc[nbd];
        t = __builtin_amdgcn_mfma_f32_16x16x32_bf16(vah, pbh, t, 0, 0, 0);
        t = __builtin_amdgcn_mfma_f32_16x16x32_bf16(vah, pbl, t, 0, 0, 0);
        t = __builtin_amdgcn_mfma_f32_16x16x32_bf16(val, pbh, t, 0, 0, 0);
        oacc[nbd] = t;
      }
      __builtin_amdgcn_s_setprio(0);
    }

    // phase epilogue: per-lane normalize; float4 stores (d = nbd*16 + quad*4 + r)
    float inv = 1.0f / lrow;
#pragma unroll
    for (int nbd = 0; nbd < 8; nbd++) {
      f32x4 o = oacc[nbd] * inv;
      *(f32x4*)&O[((size_t)qrow * NQ_HEADS + head) * HEAD_DIM + nbd * 16 + quad * 4] = o;
    }
  }
}

// ---------- head-Hadamard (32) + per-token int4 fake-quant ----------
__global__ __launch_bounds__(128) void headhad_quant(const float* __restrict__ attn,
                                                     unsigned short* __restrict__ Aq,
                                                     float* __restrict__ Sa) {
  const int t = blockIdx.x, d = threadIdx.x; // 128 threads, one d-column each
  float x[32];
#pragma unroll
  for (int h = 0; h < 32; h++) x[h] = attn[(size_t)t * 4096 + h * 128 + d];
#pragma unroll
  for (int s = 1; s < 32; s <<= 1) {
#pragma unroll
    for (int i = 0; i < 32; i++) {
      if (!(i & s)) {
        float u = x[i], v = x[i | s];
        x[i] = u + v; x[i | s] = u - v;
      }
    }
  }
  float amax = 0.f;
#pragma unroll
  for (int h = 0; h < 32; h++) { x[h] *= SCALE_H32; amax = fmaxf(amax, fabsf(x[h])); }
#pragma unroll
  for (int mm = 1; mm < 64; mm <<= 1) amax = fmaxf(amax, __shfl_xor(amax, mm, 64));
  __shared__ float red[2];
  if ((threadIdx.x & 63) == 0) red[threadIdx.x >> 6] = amax;
  __syncthreads();
  amax = fmaxf(red[0], red[1]);
  float s = fmaxf(amax / 7.0f, 1e-8f);
#pragma unroll
  for (int h = 0; h < 32; h++) {
    float q = rintf(x[h] / s);
    q = fminf(fmaxf(q, -8.f), 7.f);
    Aq[(size_t)t * 4096 + h * 128 + d] = f2bf(q);
  }
  if (threadIdx.x == 0) Sa[t] = s;
}

// ---------- launch ----------
extern "C" void kernel_launch(void* const* d_in, const int* in_sizes, int n_in,
                              void* d_out, int out_size, void* d_ws, size_t ws_size,
                              hipStream_t stream) {
  const int*   positions = (const int*)d_in[0];
  const float* hidden    = (const float*)d_in[1];
  const float* qkv_w     = (const float*)d_in[2];
  const float* qkv_b     = (const float*)d_in[3];
  const float* o_w       = (const float*)d_in[4];
  float* out = (float*)d_out;
  char* ws = (char*)d_ws;

  // region map (total ~160.1 MB)
  unsigned short* wq   = (unsigned short*)(ws + 0);          // 6144x4096 bf16 ; later owq 4096x4096
  unsigned short* xq   = (unsigned short*)(ws + 50331648);   // 2048x4096 bf16 ; later vth/vtl then aq
  float*          qkv  = (float*)(ws + 67108864);            // 2048x6144 f32 ; later attn f32
  unsigned short* qh   = (unsigned short*)(ws + 117440512);  // 2048x32x128
  unsigned short* ql   = (unsigned short*)(ws + 134217728);
  unsigned short* kh   = (unsigned short*)(ws + 150994944);  // 2048x8x128
  unsigned short* kl   = (unsigned short*)(ws + 155189248);
  unsigned short* vh   = (unsigned short*)(ws + 159383552);
  unsigned short* vl   = (unsigned short*)(ws + 163577856);
  float* s_x  = (float*)(ws + 167772160);
  float* s_w  = (float*)(ws + 167780352);
  float* s_a  = (float*)(ws + 167804928);
  float* s_ow = (float*)(ws + 167813120);
  unsigned short* owq  = wq;                                 // reuse R0 after GEMM1
  unsigned short* aq   = xq;                                 // reuse R1 after attn
  unsigned short* vth  = (unsigned short*)(ws + 50331648);   // inside R1 (xq dead after GEMM1)
  unsigned short* vtl  = (unsigned short*)(ws + 54525952);
  float* attnbuf       = qkv;                                // reuse R2 after rope

  // 1. quantize activations + qkv weights (single-pass)
  quant_rows<<<T_SEQ, 256, 0, stream>>>(hidden, xq, s_x, HIDDEN);
  quant_rows<<<QKV_N, 256, 0, stream>>>(qkv_w, wq, s_w, HIDDEN);
  // 2. QKV GEMM (exact int4 dot in bf16 MFMA)
  gemm_q4<<<dim3(QKV_N / 128, T_SEQ / 128), 256, 0, stream>>>(xq, wq, s_x, s_w, qkv_b,
                                                              qkv, T_SEQ, QKV_N, HIDDEN, 1);
  // 3. RoPE + Hadamard-128, hi/lo split outputs
  rope_had_kernel<<<(T_SEQ * 48) / 4, 256, 0, stream>>>(positions, qkv, qh, ql, kh, kl, vh, vl);
  // 3b. V transpose into [hk][d][t] (R1 is free now)
  vtrans_kernel<<<dim3(T_SEQ / 64, NKV_HEADS), 256, 0, stream>>>(vh, vl, vth, vtl);
  // 4. quantize o_w (into reused R0)
  quant_rows<<<HIDDEN, 256, 0, stream>>>(o_w, owq, s_ow, HIDDEN);
  // 5. attention: 2-head blocks, 1 barrier/tile, full K+V dbuf; writes into reused R2
  attn_kernel<<<dim3(256), 512, 0, stream>>>(qh, ql, kh, kl, vth, vtl, attnbuf);
  // 6. head-Hadamard + per-token fake-quant (into reused R1; vth/vtl dead)
  headhad_quant<<<T_SEQ, 128, 0, stream>>>(attnbuf, aq, s_a);
  // 7. O-proj GEMM
  gemm_q4<<<dim3(HIDDEN / 128, T_SEQ / 128), 256, 0, stream>>>(aq, owq, s_a, s_ow, nullptr,
                                                               out, T_SEQ, HIDDEN, HIDDEN, 0);
}

// Round 4
// 621.573 us; speedup vs baseline: 1.0858x; 1.0330x over previous
//
#include <hip/hip_runtime.h>
#include <hip/hip_bf16.h>

// ---------- types ----------
typedef __bf16 bf16x8 __attribute__((ext_vector_type(8)));
typedef unsigned short u16x8 __attribute__((ext_vector_type(8)));
typedef unsigned short u16x4 __attribute__((ext_vector_type(4)));
typedef float f32x4 __attribute__((ext_vector_type(4)));
typedef __attribute__((address_space(3))) unsigned short lds_u16;

__device__ __forceinline__ unsigned short f2bf(float f) {
  unsigned u = __float_as_uint(f);
  u += 0x7FFF + ((u >> 16) & 1);   // RNE to bf16
  return (unsigned short)(u >> 16);
}
__device__ __forceinline__ unsigned short f2bf_trunc(float f) {
  return (unsigned short)(__float_as_uint(f) >> 16);  // RTZ: fine for hi/lo splits
}
__device__ __forceinline__ float bf2f(unsigned short h) {
  return __uint_as_float(((unsigned)h) << 16);
}
__device__ __forceinline__ void gl_lds16(const void* g, lds_u16* l) {
  __builtin_amdgcn_global_load_lds((const __attribute__((address_space(1))) void*)g,
                                   (__attribute__((address_space(3))) void*)l, 16, 0, 0);
}

#define T_SEQ 2048
#define HIDDEN 4096
#define NQ_HEADS 32
#define NKV_HEADS 8
#define HEAD_DIM 128
#define QKV_N 6144
#define SCALE_QK 0.08838834764831845f   /* 1/sqrt(128) */
#define SCALE_H128 0.08838834764831845f /* 1/sqrt(128) */
#define SCALE_H32 0.17677669529663687f  /* 1/sqrt(32) */

// ---------- per-row int4 fake-quant, single-pass (row cached in registers) ----------
__global__ __launch_bounds__(256) void quant_rows(const float* __restrict__ X,
                                                  unsigned short* __restrict__ Q,
                                                  float* __restrict__ S, int C) {
  int row = blockIdx.x;
  int tid = threadIdx.x;
  const f32x4* x4 = (const f32x4*)(X + (size_t)row * C);
  f32x4 v[4];
  float amax = 0.f;
#pragma unroll
  for (int r = 0; r < 4; r++) {
    v[r] = x4[tid + r * 256];
#pragma unroll
    for (int e = 0; e < 4; e++) amax = fmaxf(amax, fabsf(v[r][e]));
  }
#pragma unroll
  for (int mm = 1; mm < 64; mm <<= 1) amax = fmaxf(amax, __shfl_xor(amax, mm, 64));
  __shared__ float red[4];
  if ((tid & 63) == 0) red[tid >> 6] = amax;
  __syncthreads();
  amax = fmaxf(fmaxf(red[0], red[1]), fmaxf(red[2], red[3]));
  float s = fmaxf(amax / 7.0f, 1e-8f);  // exact div to match reference
#pragma unroll
  for (int r = 0; r < 4; r++) {
    u16x4 q;
#pragma unroll
    for (int e = 0; e < 4; e++) {
      float wv = rintf(v[r][e] / s);    // RNE == jnp.round, exact div
      wv = fminf(fmaxf(wv, -8.f), 7.f);
      q[e] = f2bf(wv);                  // exact (small int)
    }
    *(u16x4*)&Q[(size_t)row * C + (tid + r * 256) * 4] = q;
  }
  if (tid == 0) S[row] = s;
}

// ---------- bf16(int-code) GEMM v2: A+B LDS double-buffer, 1 barrier per K-step ------
// attn-v6 pipeline: {vmcnt(0) on OWN prefetch (aged one full iteration); s_barrier;
// issue prefetch k+1 into the OTHER buffer; ds_read cur; MFMA}. Race-free: each wave
// drains its own loads before the rendezvous (tile k fully resident after barrier k);
// writes after barrier k target the buffer last read at iteration k-1, whose reads
// completed (register dependency) before any wave reached barrier k.
// NOTE: all LDS offsets in SHORT units; one buffer = 128*32 = 4096 shorts.
__global__ __launch_bounds__(256) void gemm_q4(const unsigned short* __restrict__ A,
                                               const unsigned short* __restrict__ B,
                                               const float* __restrict__ sa,
                                               const float* __restrict__ sb,
                                               const float* __restrict__ bias,
                                               float* __restrict__ C,
                                               int M, int N, int K, int hasBias) {
  __shared__ unsigned short As[2 * 128 * 32];
  __shared__ unsigned short Bs[2 * 128 * 32];
  lds_u16* As3 = (lds_u16*)As;
  lds_u16* Bs3 = (lds_u16*)Bs;
  const int tid = threadIdx.x;
  const int lane = tid & 63;
  const int w = tid >> 6;
  const int wm = w >> 1, wn = w & 1;
  const int quad = lane >> 4, l16 = lane & 15;
  const int m0 = blockIdx.y * 128, n0 = blockIdx.x * 128;

  // staging granules (2 x 16B per thread per matrix), same swizzle as the m97 version
  const int u0 = w * 64 + lane;
  const int u1 = 256 + u0;
  const int row0 = u0 >> 2, col0 = (u0 & 3) ^ ((row0 >> 1) & 3);
  const int row1 = u1 >> 2, col1 = (u1 & 3) ^ ((row1 >> 1) & 3);
  const size_t ga0 = (size_t)(m0 + row0) * K + col0 * 8;
  const size_t ga1 = (size_t)(m0 + row1) * K + col1 * 8;
  const size_t gb0 = (size_t)(n0 + row0) * K + col0 * 8;
  const size_t gb1 = (size_t)(n0 + row1) * K + col1 * 8;
  const int d0 = w * 512;          // LDS dest base within buffer (shorts), wave-uniform
  const int d1 = 2048 + w * 512;

  f32x4 acc[4][4] = {};
  const int nk = K >> 5;

  // prologue: tile 0 -> buf 0 (one cold start per block)
  gl_lds16(&A[ga0], &As3[d0]);
  gl_lds16(&A[ga1], &As3[d1]);
  gl_lds16(&B[gb0], &Bs3[d0]);
  gl_lds16(&B[gb1], &Bs3[d1]);

#pragma unroll 1
  for (int kt = 0; kt < nk; kt++) {
    const int cur = kt & 1;
    // own prefetch aged a full iteration; rendezvous makes tile kt resident for all
    asm volatile("s_waitcnt vmcnt(0)" ::: "memory");
    __builtin_amdgcn_s_barrier();
    if (kt + 1 < nk) {
      const int nb = (cur ^ 1) * 4096;             // OTHER buffer base, in shorts
      const size_t ko = (size_t)(kt + 1) * 32;
      gl_lds16(&A[ga0 + ko], &As3[nb + d0]);
      gl_lds16(&A[ga1 + ko], &As3[nb + d1]);
      gl_lds16(&B[gb0 + ko], &Bs3[nb + d0]);
      gl_lds16(&B[gb1 + ko], &Bs3[nb + d1]);
    }
    const unsigned short* Ac = As + cur * 4096;
    const unsigned short* Bc = Bs + cur * 4096;
    bf16x8 af[4], bfr[4];
#pragma unroll
    for (int i = 0; i < 4; i++) {
      int ra = wm * 64 + i * 16 + l16;
      int rb = wn * 64 + i * 16 + l16;
      af[i]  = *(const bf16x8*)&Ac[ra * 32 + (quad ^ ((ra >> 1) & 3)) * 8];
      bfr[i] = *(const bf16x8*)&Bc[rb * 32 + (quad ^ ((rb >> 1) & 3)) * 8];
    }
    __builtin_amdgcn_s_setprio(1);
#pragma unroll
    for (int i = 0; i < 4; i++)
#pragma unroll
      for (int j = 0; j < 4; j++)
        acc[i][j] = __builtin_amdgcn_mfma_f32_16x16x32_bf16(af[i], bfr[j], acc[i][j], 0, 0, 0);
    __builtin_amdgcn_s_setprio(0);
  }

#pragma unroll
  for (int i = 0; i < 4; i++) {
#pragma unroll
    for (int reg = 0; reg < 4; reg++) {
      int m = m0 + wm * 64 + i * 16 + quad * 4 + reg;
      float sm = sa[m];
#pragma unroll
      for (int j = 0; j < 4; j++) {
        int n = n0 + wn * 64 + j * 16 + l16;
        float v = acc[i][j][reg] * sm * sb[n];
        if (hasBias) v += bias[n];
        C[(size_t)m * N + n] = v;
      }
    }
  }
}

// ---------- RoPE + Hadamard-128 (q,k) and plain split (v); outputs hi/lo bf16 ----------
__global__ __launch_bounds__(256) void rope_had_kernel(const int* __restrict__ pos,
                                                       const float* __restrict__ qkv,
                                                       unsigned short* __restrict__ QH, unsigned short* __restrict__ QL,
                                                       unsigned short* __restrict__ KH, unsigned short* __restrict__ KL,
                                                       unsigned short* __restrict__ VH, unsigned short* __restrict__ VL) {
  const int w = threadIdx.x >> 6, lane = threadIdx.x & 63;
  const int vec = blockIdx.x * 4 + w;   // wave-uniform branch below
  int t, h; const float* src; unsigned short *dH, *dL; size_t o; bool doRot;
  if (vec < T_SEQ * NQ_HEADS) {
    t = vec >> 5; h = vec & 31;
    src = qkv + (size_t)t * QKV_N + h * HEAD_DIM;
    dH = QH; dL = QL; o = ((size_t)t * NQ_HEADS + h) * HEAD_DIM; doRot = true;
  } else if (vec < T_SEQ * (NQ_HEADS + NKV_HEADS)) {
    int i2 = vec - T_SEQ * NQ_HEADS; t = i2 >> 3; h = i2 & 7;
    src = qkv + (size_t)t * QKV_N + 4096 + h * HEAD_DIM;
    dH = KH; dL = KL; o = ((size_t)t * NKV_HEADS + h) * HEAD_DIM; doRot = true;
  } else {
    int i2 = vec - T_SEQ * (NQ_HEADS + NKV_HEADS); t = i2 >> 3; h = i2 & 7;
    src = qkv + (size_t)t * QKV_N + 5120 + h * HEAD_DIM;
    dH = VH; dL = VL; o = ((size_t)t * NKV_HEADS + h) * HEAD_DIM; doRot = false;
  }
  float a = src[lane], b = src[lane + 64];
  if (doRot) {
    float p = (float)pos[t];
    float fr = exp2f(-0.207620506f * (float)lane);   // 10000^-(lane/64)
    float ang = p * fr;
    float cs = cosf(ang), sn = sinf(ang);
    float na = a * cs - b * sn;
    float nb = b * cs + a * sn;
    // FWHT-128: stride-64 stage in-register, strides 1..32 via shuffles
    a = na + nb; b = na - nb;
#pragma unroll
    for (int mm = 1; mm <= 32; mm <<= 1) {
      float pa = __shfl_xor(a, mm, 64);
      float pb = __shfl_xor(b, mm, 64);
      bool hi = (lane & mm) != 0;
      a = hi ? (pa - a) : (a + pa);
      b = hi ? (pb - b) : (b + pb);
    }
    a *= SCALE_H128; b *= SCALE_H128;
  }
  unsigned short ah = f2bf(a), bh = f2bf(b);
  dH[o + lane] = ah;       dH[o + lane + 64] = bh;
  dL[o + lane] = f2bf(a - bf2f(ah));
  dL[o + lane + 64] = f2bf(b - bf2f(bh));
}

// ---------- V transpose: [t][hk][128] hi/lo -> V^T [hk][128][2048] hi/lo ----------
__global__ __launch_bounds__(256) void vtrans_kernel(const unsigned short* __restrict__ Vh,
                                                     const unsigned short* __restrict__ Vl,
                                                     unsigned short* __restrict__ VtH,
                                                     unsigned short* __restrict__ VtL) {
  __shared__ unsigned short sm[17408];  // 2 x 64x136
  unsigned short* SH = sm;
  unsigned short* SL = sm + 8704;
  const int tid = threadIdx.x;
  const int t0 = blockIdx.x * 64, h = blockIdx.y;
#pragma unroll
  for (int r = 0; r < 4; r++) {
    int G = tid + r * 256;             // 1024 granules of 8 shorts
    int row = G >> 4, g = G & 15;
    size_t src = ((size_t)(t0 + row) * NKV_HEADS + h) * HEAD_DIM + g * 8;
    *(u16x8*)&SH[row * 136 + g * 8] = *(const u16x8*)&Vh[src];
    *(u16x8*)&SL[row * 136 + g * 8] = *(const u16x8*)&Vl[src];
  }
  __syncthreads();
#pragma unroll
  for (int r = 0; r < 4; r++) {
    int G = tid + r * 256;
    int d = G >> 3, gt = G & 7;
    u16x8 a, b;
#pragma unroll
    for (int e = 0; e < 8; e++) {
      a[e] = SH[(gt * 8 + e) * 136 + d];
      b[e] = SL[(gt * 8 + e) * 136 + d];
    }
    size_t dst = ((size_t)h * HEAD_DIM + d) * T_SEQ + t0 + gt * 8;
    *(u16x8*)&VtH[dst] = a;
    *(u16x8*)&VtL[dst] = b;
  }
}

// ---------- flash attention v6: 2-head blocks, full K+V double-buffer, 1 barrier/tile -
__global__ __launch_bounds__(512, 2) void attn_kernel(const unsigned short* __restrict__ Qh, const unsigned short* __restrict__ Ql,
                                                      const unsigned short* __restrict__ Kh, const unsigned short* __restrict__ Kl,
                                                      const unsigned short* __restrict__ VtH, const unsigned short* __restrict__ VtL,
                                                      float* __restrict__ O) {
  __shared__ unsigned short smem[40960];   // 81920 B
  // K buf c: [c*8192, c*8192+4096) = KH, +4096 = KL   (phys g = log ^ (row&7))
  // V buf c: 16384 + c*8192: VH, +4096 = VL           (phys g = log ^ ((d>>1)&3))
  // Ps: 32768 + w*1024 per wave: hi[16x32], lo[16x32]
  const int tid = threadIdx.x, lane = tid & 63, w = tid >> 6;
  const int quad = lane >> 4, l16 = lane & 15;

  const int b = blockIdx.x;
  const int hk = b & 7;                  // round-robin dispatch: XCD x owns kv-head x
  const int idx = b >> 3;                // 0..31
  const int hp = idx & 1;                // head pair within kv-group
  const int u = idx >> 1;                // 0..15 ; phases run qt=u then qt=31-u
  const int head = hk * 4 + hp * 2 + (w >> 2);
  const int ww = w & 3;                  // q-row group within the 64-row tile

  // staging granule geometry (per thread, buffer-relative); 512 granules per matrix
  const int kr = tid >> 4, kg = (tid & 15) ^ (kr & 7);
  const size_t ko = ((size_t)kr * NKV_HEADS + hk) * HEAD_DIM + kg * 8;
  const int vd = tid >> 2, vg = (tid & 3) ^ ((vd >> 1) & 3);
  const size_t vo = ((size_t)hk * HEAD_DIM + vd) * T_SEQ + vg * 8;
  const size_t kTile = (size_t)32 * NKV_HEADS * HEAD_DIM;

  unsigned short* myP = smem + 32768 + w * 1024;
  const int swP = (l16 & 3) ^ ((l16 >> 2) & 3);

#pragma unroll 1
  for (int ph = 0; ph < 2; ph++) {
    const int qt = ph ? (31 - u) : u;
    const int q0 = qt * 64;
    const int qrow = q0 + ww * 16 + l16;     // this lane's q (softmax/O column)
    const int wqmax = q0 + ww * 16 + 15;
    const int nkt = 2 * qt + 2;

    // Q fragments (B-operand of S^T): lane l16 = q, quad*8+j = dim
    bf16x8 qbh[4], qbl[4];
#pragma unroll
    for (int kf = 0; kf < 4; kf++) {
      size_t g = ((size_t)qrow * NQ_HEADS + head) * HEAD_DIM + kf * 32 + quad * 8;
      qbh[kf] = *(const bf16x8*)&Qh[g];
      qbl[kf] = *(const bf16x8*)&Ql[g];
    }
    f32x4 oacc[8] = {};
    float mrow = -__builtin_inff();
    float lrow = 0.f;

    if (ph == 0) {
      // cold start: stage tile 0 into buf 0 (phase-1 tile 0 is staged by phase-0's
      // last iteration, so this runs once per block)
      gl_lds16(&Kh[ko],  (lds_u16*)&smem[w * 512]);
      gl_lds16(&Kl[ko],  (lds_u16*)&smem[4096 + w * 512]);
      gl_lds16(&VtH[vo], (lds_u16*)&smem[16384 + w * 512]);
      gl_lds16(&VtL[vo], (lds_u16*)&smem[16384 + 4096 + w * 512]);
    }

#pragma unroll 1
    for (int kt = 0; kt < nkt; kt++) {
      const int cur = kt & 1;
      const unsigned short* KcH = smem + cur * 8192;
      const unsigned short* KcL = KcH + 4096;
      const unsigned short* VcH = smem + 16384 + cur * 8192;
      const unsigned short* VcL = VcH + 4096;
      // ---- the one barrier: own prefetch (aged a full iteration) drained, then
      // rendezvous -> tile kt resident in LDS for all waves; prev buffer free ----
      asm volatile("s_waitcnt vmcnt(0)" ::: "memory");
      __builtin_amdgcn_s_barrier();
      // prefetch next tile (tile kt+1, or phase-1 tile 0 from phase-0's last iter)
      {
        int tn = -1;
        if (kt + 1 < nkt) tn = kt + 1;
        else if (ph == 0) tn = 0;            // phase-1 tile 0 -> buf 0 (parity: nkt even)
        if (tn >= 0) {
          const int nb = tn & 1;
          unsigned short* KnB = smem + nb * 8192;
          unsigned short* VnB = smem + 16384 + nb * 8192;
          size_t kOff = (size_t)tn * kTile;
          size_t vOff = (size_t)tn * 32;
          gl_lds16(&Kh[kOff + ko],  (lds_u16*)&KnB[w * 512]);
          gl_lds16(&Kl[kOff + ko],  (lds_u16*)&KnB[4096 + w * 512]);
          gl_lds16(&VtH[vOff + vo], (lds_u16*)&VnB[w * 512]);
          gl_lds16(&VtL[vOff + vo], (lds_u16*)&VnB[4096 + w * 512]);
        }
      }
      const bool active = (kt * 32 <= wqmax);   // wave-uniform
      if (!active) continue;

      // S^T = K . Q^T  (A=K, B=Q; D col = q = l16, row = key)
      f32x4 sc[2] = {};
      __builtin_amdgcn_s_setprio(1);
#pragma unroll
      for (int kf = 0; kf < 4; kf++) {
        bf16x8 kah[2], kal[2];
#pragma unroll
        for (int mb = 0; mb < 2; mb++) {
          int row = mb * 16 + l16;
          int phys = (kf * 4 + quad) ^ (l16 & 7);
          kah[mb] = *(const bf16x8*)&KcH[row * 128 + phys * 8];
          kal[mb] = *(const bf16x8*)&KcL[row * 128 + phys * 8];
        }
#pragma unroll
        for (int mb = 0; mb < 2; mb++) {
          sc[mb] = __builtin_amdgcn_mfma_f32_16x16x32_bf16(kah[mb], qbh[kf], sc[mb], 0, 0, 0);
          sc[mb] = __builtin_amdgcn_mfma_f32_16x16x32_bf16(kah[mb], qbl[kf], sc[mb], 0, 0, 0);
          sc[mb] = __builtin_amdgcn_mfma_f32_16x16x32_bf16(kal[mb], qbh[kf], sc[mb], 0, 0, 0);
        }
      }
      __builtin_amdgcn_s_setprio(0);

      // causal mask, raw-score domain (diagonal tiles only; wave-uniform test)
      if (kt * 32 + 31 > q0 + ww * 16) {
#pragma unroll
        for (int mb = 0; mb < 2; mb++)
#pragma unroll
          for (int r = 0; r < 4; r++) {
            int kg2 = kt * 32 + mb * 16 + quad * 4 + r;
            if (kg2 > qrow) sc[mb][r] = -__builtin_inff();
          }
      }

      // online softmax in RAW score domain; 1/sqrt(128) folded into exp via fma
      float tmax = sc[0][0];
#pragma unroll
      for (int r = 1; r < 4; r++) tmax = fmaxf(tmax, sc[0][r]);
#pragma unroll
      for (int r = 0; r < 4; r++) tmax = fmaxf(tmax, sc[1][r]);
      tmax = fmaxf(tmax, __shfl_xor(tmax, 16, 64));
      tmax = fmaxf(tmax, __shfl_xor(tmax, 32, 64));
      // defer-max (T13): skip O/l rescale while growth <= 4 in scaled domain
      if (!__all(tmax <= mrow + 45.2548f)) {
        float mnew = fmaxf(mrow, tmax);
        float alpha = __expf((mrow - mnew) * SCALE_QK);
        mrow = mnew;
        lrow *= alpha;
#pragma unroll
        for (int nbd = 0; nbd < 8; nbd++) oacc[nbd] *= alpha;
      }
      float negm = -mrow * SCALE_QK;
      float rs = 0.f;
#pragma unroll
      for (int mb = 0; mb < 2; mb++)
#pragma unroll
        for (int r = 0; r < 4; r++) {
          float p = __expf(__builtin_fmaf(sc[mb][r], SCALE_QK, negm));
          sc[mb][r] = p;
          rs += p;
        }
      rs += __shfl_xor(rs, 16, 64);
      rs += __shfl_xor(rs, 32, 64);
      lrow += rs;

      // pack P hi/lo into per-wave LDS [q=l16 row][32 keys], swizzled b64 writes
#pragma unroll
      for (int mb = 0; mb < 2; mb++) {
        u16x4 h4, l4;
#pragma unroll
        for (int r = 0; r < 4; r++) {
          float p = sc[mb][r];
          unsigned short hsh = f2bf_trunc(p);
          h4[r] = hsh;
          l4[r] = f2bf_trunc(p - bf2f(hsh));  // residual >= 0; trunc err 2^-16 rel
        }
        int phys = (mb * 2 + (quad >> 1)) ^ swP;
        int addr = l16 * 32 + phys * 8 + (quad & 1) * 4;
        *(u16x4*)&myP[addr] = h4;
        *(u16x4*)&myP[512 + addr] = l4;
      }

      // O^T += V^T . P  (A=V^T, B=P; D col = q = l16, row = d); V resident (prefetched)
      bf16x8 pbh = *(const bf16x8*)&myP[l16 * 32 + (quad ^ swP) * 8];
      bf16x8 pbl = *(const bf16x8*)&myP[512 + l16 * 32 + (quad ^ swP) * 8];
      __builtin_amdgcn_s_setprio(1);
#pragma unroll
      for (int nbd = 0; nbd < 8; nbd++) {
        int d = nbd * 16 + l16;
        int physv = quad ^ ((d >> 1) & 3);
        bf16x8 vah = *(const bf16x8*)&VcH[d * 32 + physv * 8];
        bf16x8 val = *(const bf16x8*)&VcL[d * 32 + physv * 8];
        f32x4 t = oacc[nbd];
        t = __builtin_amdgcn_mfma_f32_16x16x32_bf16(vah, pbh, t, 0, 0, 0);
        t = __builtin_amdgcn_mfma_f32_16x16x32_bf16(vah, pbl, t, 0, 0, 0);
        t = __builtin_amdgcn_mfma_f32_16x16x32_bf16(val, pbh, t, 0, 0, 0);
        oacc[nbd] = t;
      }
      __builtin_amdgcn_s_setprio(0);
    }

    // phase epilogue: per-lane normalize; float4 stores (d = nbd*16 + quad*4 + r)
    float inv = 1.0f / lrow;
#pragma unroll
    for (int nbd = 0; nbd < 8; nbd++) {
      f32x4 o = oacc[nbd] * inv;
      *(f32x4*)&O[((size_t)qrow * NQ_HEADS + head) * HEAD_DIM + nbd * 16 + quad * 4] = o;
    }
  }
}

// ---------- head-Hadamard (32) + per-token int4 fake-quant ----------
__global__ __launch_bounds__(128) void headhad_quant(const float* __restrict__ attn,
                                                     unsigned short* __restrict__ Aq,
                                                     float* __restrict__ Sa) {
  const int t = blockIdx.x, d = threadIdx.x; // 128 threads, one d-column each
  float x[32];
#pragma unroll
  for (int h = 0; h < 32; h++) x[h] = attn[(size_t)t * 4096 + h * 128 + d];
#pragma unroll
  for (int s = 1; s < 32; s <<= 1) {
#pragma unroll
    for (int i = 0; i < 32; i++) {
      if (!(i & s)) {
        float u = x[i], v = x[i | s];
        x[i] = u + v; x[i | s] = u - v;
      }
    }
  }
  float amax = 0.f;
#pragma unroll
  for (int h = 0; h < 32; h++) { x[h] *= SCALE_H32; amax = fmaxf(amax, fabsf(x[h])); }
#pragma unroll
  for (int mm = 1; mm < 64; mm <<= 1) amax = fmaxf(amax, __shfl_xor(amax, mm, 64));
  __shared__ float red[2];
  if ((threadIdx.x & 63) == 0) red[threadIdx.x >> 6] = amax;
  __syncthreads();
  amax = fmaxf(red[0], red[1]);
  float s = fmaxf(amax / 7.0f, 1e-8f);
#pragma unroll
  for (int h = 0; h < 32; h++) {
    float q = rintf(x[h] / s);
    q = fminf(fmaxf(q, -8.f), 7.f);
    Aq[(size_t)t * 4096 + h * 128 + d] = f2bf(q);
  }
  if (threadIdx.x == 0) Sa[t] = s;
}

// ---------- launch ----------
extern "C" void kernel_launch(void* const* d_in, const int* in_sizes, int n_in,
                              void* d_out, int out_size, void* d_ws, size_t ws_size,
                              hipStream_t stream) {
  const int*   positions = (const int*)d_in[0];
  const float* hidden    = (const float*)d_in[1];
  const float* qkv_w     = (const float*)d_in[2];
  const float* qkv_b     = (const float*)d_in[3];
  const float* o_w       = (const float*)d_in[4];
  float* out = (float*)d_out;
  char* ws = (char*)d_ws;

  // region map (total ~160.1 MB)
  unsigned short* wq   = (unsigned short*)(ws + 0);          // 6144x4096 bf16 ; later owq 4096x4096
  unsigned short* xq   = (unsigned short*)(ws + 50331648);   // 2048x4096 bf16 ; later vth/vtl then aq
  float*          qkv  = (float*)(ws + 67108864);            // 2048x6144 f32 ; later attn f32
  unsigned short* qh   = (unsigned short*)(ws + 117440512);  // 2048x32x128
  unsigned short* ql   = (unsigned short*)(ws + 134217728);
  unsigned short* kh   = (unsigned short*)(ws + 150994944);  // 2048x8x128
  unsigned short* kl   = (unsigned short*)(ws + 155189248);
  unsigned short* vh   = (unsigned short*)(ws + 159383552);
  unsigned short* vl   = (unsigned short*)(ws + 163577856);
  float* s_x  = (float*)(ws + 167772160);
  float* s_w  = (float*)(ws + 167780352);
  float* s_a  = (float*)(ws + 167804928);
  float* s_ow = (float*)(ws + 167813120);
  unsigned short* owq  = wq;                                 // reuse R0 after GEMM1
  unsigned short* aq   = xq;                                 // reuse R1 after attn
  unsigned short* vth  = (unsigned short*)(ws + 50331648);   // inside R1 (xq dead after GEMM1)
  unsigned short* vtl  = (unsigned short*)(ws + 54525952);
  float* attnbuf       = qkv;                                // reuse R2 after rope

  // 1. quantize activations + qkv weights (single-pass)
  quant_rows<<<T_SEQ, 256, 0, stream>>>(hidden, xq, s_x, HIDDEN);
  quant_rows<<<QKV_N, 256, 0, stream>>>(qkv_w, wq, s_w, HIDDEN);
  // 2. QKV GEMM (exact int4 dot in bf16 MFMA), pipelined staging
  gemm_q4<<<dim3(QKV_N / 128, T_SEQ / 128), 256, 0, stream>>>(xq, wq, s_x, s_w, qkv_b,
                                                              qkv, T_SEQ, QKV_N, HIDDEN, 1);
  // 3. RoPE + Hadamard-128, hi/lo split outputs
  rope_had_kernel<<<(T_SEQ * 48) / 4, 256, 0, stream>>>(positions, qkv, qh, ql, kh, kl, vh, vl);
  // 3b. V transpose into [hk][d][t] (R1 is free now)
  vtrans_kernel<<<dim3(T_SEQ / 64, NKV_HEADS), 256, 0, stream>>>(vh, vl, vth, vtl);
  // 4. quantize o_w (into reused R0)
  quant_rows<<<HIDDEN, 256, 0, stream>>>(o_w, owq, s_ow, HIDDEN);
  // 5. attention: 2-head blocks, 1 barrier/tile, full K+V dbuf; writes into reused R2
  attn_kernel<<<dim3(256), 512, 0, stream>>>(qh, ql, kh, kl, vth, vtl, attnbuf);
  // 6. head-Hadamard + per-token fake-quant (into reused R1; vth/vtl dead)
  headhad_quant<<<T_SEQ, 128, 0, stream>>>(attnbuf, aq, s_a);
  // 7. O-proj GEMM, pipelined staging
  gemm_q4<<<dim3(HIDDEN / 128, T_SEQ / 128), 256, 0, stream>>>(aq, owq, s_a, s_ow, nullptr,
                                                               out, T_SEQ, HIDDEN, HIDDEN, 0);
}